// Round 1
// baseline (181.336 us; speedup 1.0000x reference)
//
#include <hip/hip_runtime.h>
#include <math.h>

// AFM layer: out_b = sum_p softmax_p(logit) * (inter_p . proj_p)
//   logit_p = sum_k relu( sum_e x_i[e]x_j[e] W[e][k] + b[k] ) * h[k]
// Key identity: proj_p enters linearly -> out_b = (sum_p w_p s_p)/(sum_p w_p),
//   w_p = exp(logit_p), s_p = sum_e x_i[e]x_j[e] proj_p[e].
// Single pass over pairs; no att_out vector; no second sweep; no max-subtraction
// (logits bounded ~|10| for N(0,1) inputs -> exp safely in fp32 range).

#define F_ 50
#define E_ 64
#define A_ 10
#define P_ 1225        // 50*49/2
#define STRIDE 68      // padded row stride (floats): (f*68+4*e4)%32 spreads 8 bank-groups
#define PPT 5          // ceil(1225/256)
#define NT 256

__global__ void afm_kernel(const float* __restrict__ x,
                           const float* __restrict__ W,
                           const float* __restrict__ bias,
                           const float* __restrict__ h,
                           const float* __restrict__ pp,
                           float* __restrict__ out) {
  __shared__ __align__(16) float sx[F_ * STRIDE];   // 13600 B
  __shared__ __align__(16) float sW[E_ * A_];       // e-major: sW[e*10+k], 2560 B
  __shared__ __align__(16) float sp[E_];
  __shared__ float sb[A_], sh[A_];
  __shared__ float rn[4], rd[4];

  const int tid = threadIdx.x;
  const int b = blockIdx.x;

  // ---- stage x[b] (50x64 fp32) into padded LDS rows, coalesced float4 ----
  const float4* xb = (const float4*)(x + (size_t)b * (F_ * E_));
  for (int idx = tid; idx < F_ * (E_ / 4); idx += NT) {  // 800 float4
    float4 v = xb[idx];
    int f = idx >> 4, c = idx & 15;
    *(float4*)&sx[f * STRIDE + c * 4] = v;
  }
  for (int idx = tid; idx < (E_ * A_) / 4; idx += NT)    // 160 float4
    ((float4*)sW)[idx] = ((const float4*)W)[idx];
  if (tid < A_) { sb[tid] = bias[tid]; sh[tid] = h[tid]; }
  if (tid < E_) sp[tid] = pp[tid];
  __syncthreads();

  // ---- pair assignment: p = tid + c*256 (lane-consecutive p => j consecutive,
  //      i near-uniform => x_i reads ~broadcast, x_j reads bank-spread) ----
  int ai[PPT], aj[PPT];
#pragma unroll
  for (int c = 0; c < PPT; ++c) {
    int p = tid + c * NT;
    int i = 0, j = 1;
    if (p < P_) {
      int rem = p;
      while (rem >= F_ - 1 - i) { rem -= F_ - 1 - i; ++i; }
      j = i + 1 + rem;
    }
    ai[c] = i * STRIDE;
    aj[c] = j * STRIDE;
  }

  float acc[PPT][A_];
  float sacc[PPT];
#pragma unroll
  for (int c = 0; c < PPT; ++c) {
    sacc[c] = 0.f;
#pragma unroll
    for (int k = 0; k < A_; ++k) acc[c][k] = 0.f;
  }

  // ---- main sweep over e in chunks of 4 ----
#pragma unroll 1
  for (int e4 = 0; e4 < E_ / 4; ++e4) {
    // W chunk: 4 e-rows x 10 k = 40 floats as 10 broadcast float4 reads
    float wf[40];
#pragma unroll
    for (int q = 0; q < 10; ++q) {
      float4 v = ((const float4*)sW)[e4 * 10 + q];
      wf[q * 4 + 0] = v.x; wf[q * 4 + 1] = v.y;
      wf[q * 4 + 2] = v.z; wf[q * 4 + 3] = v.w;
    }
    float4 pc = ((const float4*)sp)[e4];

#pragma unroll
    for (int c = 0; c < PPT; ++c) {
      float4 xi = *(const float4*)&sx[ai[c] + e4 * 4];
      float4 xj = *(const float4*)&sx[aj[c] + e4 * 4];
      float p0 = xi.x * xj.x, p1 = xi.y * xj.y;
      float p2 = xi.z * xj.z, p3 = xi.w * xj.w;
#pragma unroll
      for (int k = 0; k < A_; ++k) {
        float t = acc[c][k];
        t = fmaf(p0, wf[0 * A_ + k], t);
        t = fmaf(p1, wf[1 * A_ + k], t);
        t = fmaf(p2, wf[2 * A_ + k], t);
        t = fmaf(p3, wf[3 * A_ + k], t);
        acc[c][k] = t;
      }
      float sv = sacc[c];
      sv = fmaf(p0, pc.x, sv); sv = fmaf(p1, pc.y, sv);
      sv = fmaf(p2, pc.z, sv); sv = fmaf(p3, pc.w, sv);
      sacc[c] = sv;
    }
  }

  // ---- epilogue: logits -> w = exp(logit); num/den fold ----
  float num = 0.f, den = 0.f;
#pragma unroll
  for (int c = 0; c < PPT; ++c) {
    float lg = 0.f;
#pragma unroll
    for (int k = 0; k < A_; ++k) {
      float v = acc[c][k] + sb[k];
      v = fmaxf(v, 0.f);
      lg = fmaf(v, sh[k], lg);
    }
    float w = __expf(lg);
    if (tid + c * NT >= P_) w = 0.f;   // only c==4 can be invalid
    num = fmaf(w, sacc[c], num);
    den += w;
  }

  // ---- block reduction of (num, den): wave shuffle then LDS ----
  const int lane = tid & 63, wid = tid >> 6;
#pragma unroll
  for (int off = 32; off; off >>= 1) {
    num += __shfl_down(num, off);
    den += __shfl_down(den, off);
  }
  if (lane == 0) { rn[wid] = num; rd[wid] = den; }
  __syncthreads();
  if (tid == 0) {
    float n = rn[0] + rn[1] + rn[2] + rn[3];
    float d = rd[0] + rd[1] + rd[2] + rd[3];
    out[b] = n / d;
  }
}

extern "C" void kernel_launch(void* const* d_in, const int* in_sizes, int n_in,
                              void* d_out, int out_size, void* d_ws, size_t ws_size,
                              hipStream_t stream) {
  const float* x  = (const float*)d_in[0];
  const float* W  = (const float*)d_in[1];
  const float* bb = (const float*)d_in[2];
  const float* h  = (const float*)d_in[3];
  const float* pp = (const float*)d_in[4];
  float* out = (float*)d_out;
  const int batch = in_sizes[0] / (F_ * E_);
  afm_kernel<<<batch, NT, 0, stream>>>(x, W, bb, h, pp, out);
}

// Round 2
// 127.993 us; speedup vs baseline: 1.4168x; 1.4168x over previous
//
#include <hip/hip_runtime.h>
#include <math.h>

// AFM layer: out_b = sum_p softmax_p(logit) * (inter_p . proj_p)
//   logit_p = sum_k relu( sum_e x_i[e]x_j[e] W[e][k] + b[k] ) * h[k]
// Identity: proj enters linearly -> out_b = (sum_p w_p s_p)/(sum_p w_p),
//   w_p = exp(logit_p), s_p = sum_e x_i[e]x_j[e] proj[e].
// Round 2 fix: __launch_bounds__(256,2). Round-1 had VGPR_Count=64 (default
// 1024-thread worst-case alloc) -> acc/wf arrays spilled to scratch ->
// 161 MB HBM writeback, VALUBusy 45%. With a 256-VGPR cap the ~140 live
// regs fit; expect ~4x.

#define F_ 50
#define E_ 64
#define A_ 10
#define P_ 1225        // 50*49/2
#define STRIDE 68      // padded row stride (floats)
#define PPT 5          // ceil(1225/256)
#define NT 256

__global__ __launch_bounds__(NT, 2)
void afm_kernel(const float* __restrict__ x,
                const float* __restrict__ W,
                const float* __restrict__ bias,
                const float* __restrict__ h,
                const float* __restrict__ pp,
                float* __restrict__ out) {
  __shared__ __align__(16) float sx[F_ * STRIDE];   // 13600 B
  __shared__ __align__(16) float sW[E_ * A_];       // e-major: sW[e*10+k]
  __shared__ __align__(16) float sp[E_];
  __shared__ float sb[A_], sh[A_];
  __shared__ float rn[4], rd[4];

  const int tid = threadIdx.x;
  const int b = blockIdx.x;

  // ---- stage x[b] (50x64 fp32) into padded LDS rows, coalesced float4 ----
  const float4* xb = (const float4*)(x + (size_t)b * (F_ * E_));
  for (int idx = tid; idx < F_ * (E_ / 4); idx += NT) {  // 800 float4
    float4 v = xb[idx];
    int f = idx >> 4, c = idx & 15;
    *(float4*)&sx[f * STRIDE + c * 4] = v;
  }
  for (int idx = tid; idx < (E_ * A_) / 4; idx += NT)    // 160 float4
    ((float4*)sW)[idx] = ((const float4*)W)[idx];
  if (tid < A_) { sb[tid] = bias[tid]; sh[tid] = h[tid]; }
  if (tid < E_) sp[tid] = pp[tid];
  __syncthreads();

  // ---- pair assignment: p = tid + c*256 (lane-consecutive p => j
  //      consecutive => bank-spread; i near-uniform => ~broadcast) ----
  int ai[PPT], aj[PPT];
#pragma unroll
  for (int c = 0; c < PPT; ++c) {
    int p = tid + c * NT;
    int i = 0, j = 1;
    if (p < P_) {
      int rem = p;
      while (rem >= F_ - 1 - i) { rem -= F_ - 1 - i; ++i; }
      j = i + 1 + rem;
    }
    ai[c] = i * STRIDE;
    aj[c] = j * STRIDE;
  }

  float acc[PPT][A_];
  float sacc[PPT];
#pragma unroll
  for (int c = 0; c < PPT; ++c) {
    sacc[c] = 0.f;
#pragma unroll
    for (int k = 0; k < A_; ++k) acc[c][k] = 0.f;
  }

  // ---- main sweep over e in chunks of 4 ----
#pragma unroll 1
  for (int e4 = 0; e4 < E_ / 4; ++e4) {
    // W chunk: 4 e-rows x 10 k = 40 floats as 10 broadcast float4 reads,
    // held in regs and reused across PPT pairs
    float wf[40];
#pragma unroll
    for (int q = 0; q < 10; ++q) {
      float4 v = ((const float4*)sW)[e4 * 10 + q];
      wf[q * 4 + 0] = v.x; wf[q * 4 + 1] = v.y;
      wf[q * 4 + 2] = v.z; wf[q * 4 + 3] = v.w;
    }
    float4 pc = ((const float4*)sp)[e4];

#pragma unroll
    for (int c = 0; c < PPT; ++c) {
      float4 xi = *(const float4*)&sx[ai[c] + e4 * 4];
      float4 xj = *(const float4*)&sx[aj[c] + e4 * 4];
      float p0 = xi.x * xj.x, p1 = xi.y * xj.y;
      float p2 = xi.z * xj.z, p3 = xi.w * xj.w;
#pragma unroll
      for (int k = 0; k < A_; ++k) {
        float t = acc[c][k];
        t = fmaf(p0, wf[0 * A_ + k], t);
        t = fmaf(p1, wf[1 * A_ + k], t);
        t = fmaf(p2, wf[2 * A_ + k], t);
        t = fmaf(p3, wf[3 * A_ + k], t);
        acc[c][k] = t;
      }
      float sv = sacc[c];
      sv = fmaf(p0, pc.x, sv); sv = fmaf(p1, pc.y, sv);
      sv = fmaf(p2, pc.z, sv); sv = fmaf(p3, pc.w, sv);
      sacc[c] = sv;
    }
  }

  // ---- epilogue: logits -> w = exp(logit); num/den fold ----
  float num = 0.f, den = 0.f;
#pragma unroll
  for (int c = 0; c < PPT; ++c) {
    float lg = 0.f;
#pragma unroll
    for (int k = 0; k < A_; ++k) {
      float v = acc[c][k] + sb[k];
      v = fmaxf(v, 0.f);
      lg = fmaf(v, sh[k], lg);
    }
    float w = __expf(lg);
    if (tid + c * NT >= P_) w = 0.f;   // only c==4 can be invalid
    num = fmaf(w, sacc[c], num);
    den += w;
  }

  // ---- block reduction of (num, den): wave shuffle then LDS ----
  const int lane = tid & 63, wid = tid >> 6;
#pragma unroll
  for (int off = 32; off; off >>= 1) {
    num += __shfl_down(num, off);
    den += __shfl_down(den, off);
  }
  if (lane == 0) { rn[wid] = num; rd[wid] = den; }
  __syncthreads();
  if (tid == 0) {
    float n = rn[0] + rn[1] + rn[2] + rn[3];
    float d = rd[0] + rd[1] + rd[2] + rd[3];
    out[b] = n / d;
  }
}

extern "C" void kernel_launch(void* const* d_in, const int* in_sizes, int n_in,
                              void* d_out, int out_size, void* d_ws, size_t ws_size,
                              hipStream_t stream) {
  const float* x  = (const float*)d_in[0];
  const float* W  = (const float*)d_in[1];
  const float* bb = (const float*)d_in[2];
  const float* h  = (const float*)d_in[3];
  const float* pp = (const float*)d_in[4];
  float* out = (float*)d_out;
  const int batch = in_sizes[0] / (F_ * E_);
  afm_kernel<<<batch, NT, 0, stream>>>(x, W, bb, h, pp, out);
}

// Round 3
// 95.397 us; speedup vs baseline: 1.9009x; 1.3417x over previous
//
#include <hip/hip_runtime.h>
#include <math.h>

// AFM layer via Gram-matrix MFMA:
//   t_k(i,j) = (X diag(W[:,k]) X^T)_ij   (11 Grams: 10 attention k's + proj p)
//   logit_ij = sum_k relu(t_k + b_k) h_k ; out = (sum exp(logit) s_ij)/(sum exp(logit))
// over pairs i<j<50. fp16 MFMA 32x32x16; 50x50 Gram = 3 upper-tri 32x32 tiles
// ((0,0),(0,1),(1,1)); 6-wave block = 2 batches, no idle waves.
// fp16 (not bf16): 2^-11 rounding -> logit err ~1e-3 << 2.16e-2 threshold.

#define F_ 50
#define E_ 64
#define A_ 10
#define XDIM 64          // F padded to 64 (rows 50..63 zeroed)
#define XSTR 72          // LDS row stride in halves (144 B, 16B-aligned rows)
#define NT 384           // 6 waves: 3 tiles x 2 batches

typedef _Float16 half8 __attribute__((ext_vector_type(8)));
typedef _Float16 half4t __attribute__((ext_vector_type(4)));
typedef float f32x16 __attribute__((ext_vector_type(16)));

__global__ __launch_bounds__(NT, 2)
void afm_mfma_kernel(const float* __restrict__ x,
                     const float* __restrict__ W,
                     const float* __restrict__ bias,
                     const float* __restrict__ h,
                     const float* __restrict__ pp,
                     float* __restrict__ out, int nbatch) {
  __shared__ __align__(16) _Float16 sXh[2 * XDIM * XSTR];  // 2 batches, 18432 B
  __shared__ __align__(16) _Float16 sWh[(A_ + 1) * E_];    // row k<10: W[:,k]; row 10: p
  __shared__ float sb[A_], sh[A_];
  __shared__ float rn[6], rd[6];

  const int tid = threadIdx.x;
  const int b0 = blockIdx.x * 2;

  // ---- stage x (2 batches, fp32 -> fp16), coalesced float4 reads ----
  for (int q = tid; q < 2 * F_ * 16; q += NT) {            // 1600 float4s
    int bb = q >= 800;
    int r4 = q - bb * 800;
    int f = r4 >> 4, e4 = r4 & 15;
    if (b0 + bb < nbatch) {
      float4 v = *(const float4*)(x + (size_t)(b0 + bb) * (F_ * E_) + f * E_ + e4 * 4);
      half4t hv = { (_Float16)v.x, (_Float16)v.y, (_Float16)v.z, (_Float16)v.w };
      *(half4t*)(sXh + bb * (XDIM * XSTR) + f * XSTR + e4 * 4) = hv;
    }
  }
  // zero pad rows 50..63 (keeps MFMA padded lanes NaN-free)
  for (int t = tid; t < 2 * 14 * 16; t += NT) {            // 448 half4 chunks
    int bb = t >= 224;
    int z = t - bb * 224;
    int f = F_ + (z >> 4), e4 = z & 15;
    half4t zv = { (_Float16)0.f, (_Float16)0.f, (_Float16)0.f, (_Float16)0.f };
    *(half4t*)(sXh + bb * (XDIM * XSTR) + f * XSTR + e4 * 4) = zv;
  }
  // stage W (e-major in global -> k-major fp16) and p as row 10
  if (tid < (A_ + 1) * 32) {
    int kk = tid >> 5, e2 = tid & 31;
    float v0, v1;
    if (kk < A_) { v0 = W[(2 * e2) * A_ + kk]; v1 = W[(2 * e2 + 1) * A_ + kk]; }
    else         { v0 = pp[2 * e2];            v1 = pp[2 * e2 + 1]; }
    sWh[kk * E_ + 2 * e2]     = (_Float16)v0;
    sWh[kk * E_ + 2 * e2 + 1] = (_Float16)v1;
  }
  if (tid < A_) { sb[tid] = bias[tid]; sh[tid] = h[tid]; }
  __syncthreads();

  // ---- wave -> (batch, tile) ----
  const int w6 = tid >> 6, lane = tid & 63;
  const int bb = (w6 >= 3), tile = w6 - bb * 3;
  const int m0 = (tile == 2) ? 32 : 0;        // tiles: (0,0),(0,32),(32,32)
  const int n0 = (tile == 0) ? 0 : 32;
  const int row = lane & 31, half = lane >> 5;
  const bool bvalid = (b0 + bb) < nbatch;

  float num = 0.f, den = 0.f;
  if (bvalid) {
    const _Float16* xb = sXh + bb * (XDIM * XSTR);
    // A/B fragments (unscaled X), 8 consecutive e per lane, held in regs
    half8 axf[4], bxf[4];
#pragma unroll
    for (int es = 0; es < 4; ++es) {
      int eoff = es * 16 + half * 8;
      axf[es] = *(const half8*)(xb + (m0 + row) * XSTR + eoff);
      bxf[es] = *(const half8*)(xb + (n0 + row) * XSTR + eoff);
    }

    // S = X diag(p) X^T  (proj Gram, kept as accumulator)
    f32x16 sacc = {0,0,0,0,0,0,0,0,0,0,0,0,0,0,0,0};
#pragma unroll
    for (int es = 0; es < 4; ++es) {
      half8 pv = *(const half8*)(sWh + A_ * E_ + es * 16 + half * 8);
      sacc = __builtin_amdgcn_mfma_f32_32x32x16_f16(axf[es] * pv, bxf[es], sacc, 0, 0, 0);
    }

    // logit accumulation over the 10 attention factors
    float lg[16];
#pragma unroll
    for (int r = 0; r < 16; ++r) lg[r] = 0.f;
#pragma unroll 1
    for (int k = 0; k < A_; ++k) {
      f32x16 acc = {0,0,0,0,0,0,0,0,0,0,0,0,0,0,0,0};
#pragma unroll
      for (int es = 0; es < 4; ++es) {
        half8 wv = *(const half8*)(sWh + k * E_ + es * 16 + half * 8);  // broadcast
        acc = __builtin_amdgcn_mfma_f32_32x32x16_f16(axf[es] * wv, bxf[es], acc, 0, 0, 0);
      }
      float bk = sb[k], hk = sh[k];
#pragma unroll
      for (int r = 0; r < 16; ++r)
        lg[r] = fmaf(fmaxf(acc[r] + bk, 0.f), hk, lg[r]);
    }

    // epilogue: mask i<j<50, fold exp into (num, den)
    const int jcol = n0 + row;   // C/D: col = lane&31
#pragma unroll
    for (int r = 0; r < 16; ++r) {
      int irow = m0 + (r & 3) + 8 * (r >> 2) + 4 * half;  // C/D row map (m74/m101)
      bool valid = (irow < jcol) && (jcol < F_);
      float w = valid ? __expf(lg[r]) : 0.f;
      num = fmaf(w, sacc[r], num);
      den += w;
    }
  }

  // ---- reduce: wave shuffle -> LDS -> per-batch combine ----
#pragma unroll
  for (int off = 32; off; off >>= 1) {
    num += __shfl_down(num, off);
    den += __shfl_down(den, off);
  }
  if (lane == 0) { rn[w6] = num; rd[w6] = den; }
  __syncthreads();
  if (tid == 0)
    out[b0] = (rn[0] + rn[1] + rn[2]) / (rd[0] + rd[1] + rd[2]);
  if (tid == 64 && b0 + 1 < nbatch)
    out[b0 + 1] = (rn[3] + rn[4] + rn[5]) / (rd[3] + rd[4] + rd[5]);
}

extern "C" void kernel_launch(void* const* d_in, const int* in_sizes, int n_in,
                              void* d_out, int out_size, void* d_ws, size_t ws_size,
                              hipStream_t stream) {
  const float* x  = (const float*)d_in[0];
  const float* W  = (const float*)d_in[1];
  const float* bb = (const float*)d_in[2];
  const float* h  = (const float*)d_in[3];
  const float* pp = (const float*)d_in[4];
  float* out = (float*)d_out;
  const int nbatch = in_sizes[0] / (F_ * E_);
  const int nblocks = (nbatch + 1) / 2;
  afm_mfma_kernel<<<nblocks, NT, 0, stream>>>(x, W, bb, h, pp, out, nbatch);
}

// Round 4
// 92.490 us; speedup vs baseline: 1.9606x; 1.0314x over previous
//
#include <hip/hip_runtime.h>
#include <math.h>

// AFM layer via Gram-matrix MFMA (fp16 32x32x16):
//   t_k(i,j) = (X diag(W[:,k]) X^T)_ij, 10 att Grams + 1 proj Gram
//   out = (sum_{i<j} exp(logit_ij) s_ij) / (sum exp(logit_ij))
// 50x50 Gram = 3 upper-tri 32x32 tiles; 6 waves = 2 batches per block.
//
// R4 changes vs R3 (theory: VGPR-limited occupancy, 2 waves/SIMD):
//  - proj-Gram (sacc) moved AFTER the k-loop -> k-loop live set ~110 regs
//  - acc initialized to bias b_k (saves 16 adds/k/wave, fuses the +b)
//  - __launch_bounds__(384,4): 128-VGPR cap -> 4 waves/SIMD

#define F_ 50
#define E_ 64
#define A_ 10
#define XDIM 64          // F padded to 64 (rows 50..63 zeroed)
#define XSTR 72          // LDS row stride in halves (144 B, 16B-aligned rows)
#define NT 384           // 6 waves: 3 tiles x 2 batches

typedef _Float16 half8 __attribute__((ext_vector_type(8)));
typedef _Float16 half4t __attribute__((ext_vector_type(4)));
typedef float f32x16 __attribute__((ext_vector_type(16)));

__global__ __launch_bounds__(NT, 4)
void afm_mfma_kernel(const float* __restrict__ x,
                     const float* __restrict__ W,
                     const float* __restrict__ bias,
                     const float* __restrict__ h,
                     const float* __restrict__ pp,
                     float* __restrict__ out, int nbatch) {
  __shared__ __align__(16) _Float16 sXh[2 * XDIM * XSTR];  // 18432 B
  __shared__ __align__(16) _Float16 sWh[(A_ + 1) * E_];    // k<10: W[:,k]; 10: p
  __shared__ float sb[A_], sh[A_];
  __shared__ float rn[6], rd[6];

  const int tid = threadIdx.x;
  const int b0 = blockIdx.x * 2;

  // ---- stage x (2 batches, fp32 -> fp16), coalesced float4 reads ----
  for (int q = tid; q < 2 * F_ * 16; q += NT) {            // 1600 float4s
    int bb = q >= 800;
    int r4 = q - bb * 800;
    int f = r4 >> 4, e4 = r4 & 15;
    if (b0 + bb < nbatch) {
      float4 v = *(const float4*)(x + (size_t)(b0 + bb) * (F_ * E_) + f * E_ + e4 * 4);
      half4t hv = { (_Float16)v.x, (_Float16)v.y, (_Float16)v.z, (_Float16)v.w };
      *(half4t*)(sXh + bb * (XDIM * XSTR) + f * XSTR + e4 * 4) = hv;
    }
  }
  // zero pad rows 50..63 (MFMA padded lanes must be 0, LDS is uninit)
  for (int t = tid; t < 2 * 14 * 16; t += NT) {
    int bb = t >= 224;
    int z = t - bb * 224;
    int f = F_ + (z >> 4), e4 = z & 15;
    half4t zv = { (_Float16)0.f, (_Float16)0.f, (_Float16)0.f, (_Float16)0.f };
    *(half4t*)(sXh + bb * (XDIM * XSTR) + f * XSTR + e4 * 4) = zv;
  }
  // stage W (e-major global -> k-major fp16) and p as row 10
  if (tid < (A_ + 1) * 32) {
    int kk = tid >> 5, e2 = tid & 31;
    float v0, v1;
    if (kk < A_) { v0 = W[(2 * e2) * A_ + kk]; v1 = W[(2 * e2 + 1) * A_ + kk]; }
    else         { v0 = pp[2 * e2];            v1 = pp[2 * e2 + 1]; }
    sWh[kk * E_ + 2 * e2]     = (_Float16)v0;
    sWh[kk * E_ + 2 * e2 + 1] = (_Float16)v1;
  }
  if (tid < A_) { sb[tid] = bias[tid]; sh[tid] = h[tid]; }
  __syncthreads();

  // ---- wave -> (batch, tile) ----
  const int w6 = tid >> 6, lane = tid & 63;
  const int bb = (w6 >= 3), tile = w6 - bb * 3;
  const int m0 = (tile == 2) ? 32 : 0;        // tiles: (0,0),(0,32),(32,32)
  const int n0 = (tile == 0) ? 0 : 32;
  const int row = lane & 31, half = lane >> 5;
  const bool bvalid = (b0 + bb) < nbatch;

  float num = 0.f, den = 0.f;
  if (bvalid) {
    const _Float16* xb = sXh + bb * (XDIM * XSTR);
    // A/B fragments (unscaled X): A[m][k]: m=lane&31, k=(lane>>5)*8+j
    half8 axf[4], bxf[4];
#pragma unroll
    for (int es = 0; es < 4; ++es) {
      int eoff = es * 16 + half * 8;
      axf[es] = *(const half8*)(xb + (m0 + row) * XSTR + eoff);
      bxf[es] = *(const half8*)(xb + (n0 + row) * XSTR + eoff);
    }

    // ---- logit accumulation over 10 attention factors ----
    float lg[16];
#pragma unroll
    for (int r = 0; r < 16; ++r) lg[r] = 0.f;
#pragma unroll 1
    for (int k = 0; k < A_; ++k) {
      float bk = sb[k], hk = sh[k];
      f32x16 acc;
#pragma unroll
      for (int r = 0; r < 16; ++r) acc[r] = bk;   // fused +b_k
#pragma unroll
      for (int es = 0; es < 4; ++es) {
        half8 wv = *(const half8*)(sWh + k * E_ + es * 16 + half * 8);  // broadcast
        acc = __builtin_amdgcn_mfma_f32_32x32x16_f16(axf[es] * wv, bxf[es], acc, 0, 0, 0);
      }
#pragma unroll
      for (int r = 0; r < 16; ++r)
        lg[r] = fmaf(fmaxf(acc[r], 0.f), hk, lg[r]);
    }

    // ---- proj Gram AFTER k-loop (keeps k-loop live set small) ----
    f32x16 sacc = {0,0,0,0,0,0,0,0,0,0,0,0,0,0,0,0};
#pragma unroll
    for (int es = 0; es < 4; ++es) {
      half8 pv = *(const half8*)(sWh + A_ * E_ + es * 16 + half * 8);
      sacc = __builtin_amdgcn_mfma_f32_32x32x16_f16(axf[es] * pv, bxf[es], sacc, 0, 0, 0);
    }

    // ---- epilogue: mask i<j<50, fold exp into (num, den) ----
    const int jcol = n0 + row;   // C/D: col = lane&31
#pragma unroll
    for (int r = 0; r < 16; ++r) {
      int irow = m0 + (r & 3) + 8 * (r >> 2) + 4 * half;  // C/D row map (m74/m101)
      bool valid = (irow < jcol) && (jcol < F_);
      float w = valid ? __expf(lg[r]) : 0.f;
      num = fmaf(w, sacc[r], num);
      den += w;
    }
  }

  // ---- reduce: wave shuffle -> LDS -> per-batch combine ----
#pragma unroll
  for (int off = 32; off; off >>= 1) {
    num += __shfl_down(num, off);
    den += __shfl_down(den, off);
  }
  if (lane == 0) { rn[w6] = num; rd[w6] = den; }
  __syncthreads();
  if (tid == 0)
    out[b0] = (rn[0] + rn[1] + rn[2]) / (rd[0] + rd[1] + rd[2]);
  if (tid == 64 && b0 + 1 < nbatch)
    out[b0 + 1] = (rn[3] + rn[4] + rn[5]) / (rd[3] + rd[4] + rd[5]);
}

extern "C" void kernel_launch(void* const* d_in, const int* in_sizes, int n_in,
                              void* d_out, int out_size, void* d_ws, size_t ws_size,
                              hipStream_t stream) {
  const float* x  = (const float*)d_in[0];
  const float* W  = (const float*)d_in[1];
  const float* bb = (const float*)d_in[2];
  const float* h  = (const float*)d_in[3];
  const float* pp = (const float*)d_in[4];
  float* out = (float*)d_out;
  const int nbatch = in_sizes[0] / (F_ * E_);
  const int nblocks = (nbatch + 1) / 2;
  afm_mfma_kernel<<<nblocks, NT, 0, stream>>>(x, W, bb, h, pp, out, nbatch);
}

// Round 5
// 87.918 us; speedup vs baseline: 2.0626x; 1.0520x over previous
//
#include <hip/hip_runtime.h>
#include <math.h>

// AFM via Gram MFMA, R5 restructure: 16x16x32 f16, ONE batch per wave.
//   t_k = X diag(W[:,k]) X^T ; logit = sum_k relu(t_k + b_k) h_k
//   out = (sum_{i<j} exp(logit) s_ij) / (sum exp(logit)),  s = X diag(p) X^T
// Gram trick: A-frag and B-frag have IDENTICAL LDS addressing (row=lane&15,
// k-chunk=lane>>4) -> one 8-fragment set (32 VGPR) serves both operands of
// all 10 upper-tri 16x16 tiles for all k. Per k: 10 independent depth-2 MFMA
// chains (latency self-hiding at 2 waves/SIMD), 2 broadcast wv loads, bias
// fused via C operand. No cross-wave reduce; one barrier (W staging).

#define F_ 50
#define E_ 64
#define A_ 10
#define XSTR 72          // halves; 144 B rows, 16B-aligned
#define NT 256           // 4 waves = 4 batches per block
#define LOG2E 1.44269504088896f

typedef _Float16 half8 __attribute__((ext_vector_type(8)));
typedef _Float16 half4t __attribute__((ext_vector_type(4)));
typedef float f32x4 __attribute__((ext_vector_type(4)));

__global__ __launch_bounds__(NT, 2)
void afm_kernel(const float* __restrict__ x,
                const float* __restrict__ W,
                const float* __restrict__ bias,
                const float* __restrict__ h,
                const float* __restrict__ pp,
                float* __restrict__ out, int nbatch) {
  __shared__ __align__(16) _Float16 sXh[4 * 64 * XSTR];   // 36864 B
  __shared__ __align__(16) _Float16 sWh[(A_ + 1) * E_];   // k<10: W[:,k]; 10: p
  __shared__ float sb[A_], sh[A_];

  const int tid = threadIdx.x;
  const int lane = tid & 63, w4 = tid >> 6;
  const int b = blockIdx.x * 4 + w4;
  const bool bvalid = b < nbatch;
  _Float16* xb = sXh + w4 * (64 * XSTR);

  // ---- each wave stages ITS OWN batch (wave-private LDS region) ----
  if (bvalid) {
    const float4* xs = (const float4*)(x + (size_t)b * (F_ * E_));
    for (int q = lane; q < F_ * 16; q += 64) {       // 800 float4
      float4 v = xs[q];
      int f = q >> 4, e4 = q & 15;
      half4t hv = {(_Float16)v.x, (_Float16)v.y, (_Float16)v.z, (_Float16)v.w};
      *(half4t*)(xb + f * XSTR + e4 * 4) = hv;
    }
  }
  // zero rows 50..63 (avoid NaN poison feeding MFMA; masked later anyway)
  for (int q = lane; q < 14 * 8; q += 64) {
    int f = F_ + (q >> 3), c = q & 7;
    half8 z = {};
    *(half8*)(xb + f * XSTR + c * 8) = z;
  }
  // ---- stage W (e-major -> k-major fp16) + p as row 10 ----
  if (tid < 11 * 16) {
    int k = tid >> 4, e4 = tid & 15;
    float v0, v1, v2, v3;
    if (k < A_) {
      v0 = W[(e4 * 4 + 0) * A_ + k]; v1 = W[(e4 * 4 + 1) * A_ + k];
      v2 = W[(e4 * 4 + 2) * A_ + k]; v3 = W[(e4 * 4 + 3) * A_ + k];
    } else {
      float4 t4 = *(const float4*)(pp + e4 * 4);
      v0 = t4.x; v1 = t4.y; v2 = t4.z; v3 = t4.w;
    }
    half4t hv = {(_Float16)v0, (_Float16)v1, (_Float16)v2, (_Float16)v3};
    *(half4t*)(sWh + k * E_ + e4 * 4) = hv;
  }
  if (tid < A_) { sb[tid] = bias[tid]; sh[tid] = h[tid] * LOG2E; }
  __syncthreads();

  float num = 0.f, den = 0.f;
  if (bvalid) {
    const int m = lane & 15, q8 = lane >> 4;
    // one fragment set serves both A and B operands (Gram symmetry)
    half8 fr[4][2];
#pragma unroll
    for (int bi = 0; bi < 4; ++bi)
#pragma unroll
      for (int es = 0; es < 2; ++es)
        fr[bi][es] = *(const half8*)(xb + (bi * 16 + m) * XSTR + es * 32 + q8 * 8);

    float lg[10][4];
#pragma unroll
    for (int t0 = 0; t0 < 10; ++t0)
#pragma unroll
      for (int r = 0; r < 4; ++r) lg[t0][r] = 0.f;

#pragma unroll 1
    for (int k = 0; k < A_; ++k) {
      half8 wv0 = *(const half8*)(sWh + k * E_ + q8 * 8);        // broadcast x4
      half8 wv1 = *(const half8*)(sWh + k * E_ + 32 + q8 * 8);
      float bk = sb[k];
      f32x4 ci = {bk, bk, bk, bk};
      half8 sa0[4];
#pragma unroll
      for (int bi = 0; bi < 4; ++bi) sa0[bi] = fr[bi][0] * wv0;  // pk_mul
      f32x4 t[10];
      {
        int idx = 0;
#pragma unroll
        for (int bi = 0; bi < 4; ++bi)
#pragma unroll
          for (int bj = bi; bj < 4; ++bj)
            t[idx++] = __builtin_amdgcn_mfma_f32_16x16x32_f16(sa0[bi], fr[bj][0], ci, 0, 0, 0);
      }
      half8 sa1[4];
#pragma unroll
      for (int bi = 0; bi < 4; ++bi) sa1[bi] = fr[bi][1] * wv1;
      {
        int idx = 0;
#pragma unroll
        for (int bi = 0; bi < 4; ++bi)
#pragma unroll
          for (int bj = bi; bj < 4; ++bj) {
            t[idx] = __builtin_amdgcn_mfma_f32_16x16x32_f16(sa1[bi], fr[bj][1], t[idx], 0, 0, 0);
            ++idx;
          }
      }
      float hk = sh[k];   // pre-scaled by log2(e)
#pragma unroll
      for (int idx = 0; idx < 10; ++idx)
#pragma unroll
        for (int r = 0; r < 4; ++r)
          lg[idx][r] = fmaf(fmaxf(t[idx][r], 0.f), hk, lg[idx][r]);
    }

    // ---- proj Gram per tile (transient 4-reg acc) + masked exp fold ----
    half8 pv0 = *(const half8*)(sWh + A_ * E_ + q8 * 8);
    half8 pv1 = *(const half8*)(sWh + A_ * E_ + 32 + q8 * 8);
    f32x4 z4 = {0.f, 0.f, 0.f, 0.f};
    int idx = 0;
#pragma unroll
    for (int bi = 0; bi < 4; ++bi) {
      half8 pa0 = fr[bi][0] * pv0;
      half8 pa1 = fr[bi][1] * pv1;
#pragma unroll
      for (int bj = bi; bj < 4; ++bj) {
        f32x4 s4 = __builtin_amdgcn_mfma_f32_16x16x32_f16(pa0, fr[bj][0], z4, 0, 0, 0);
        s4 = __builtin_amdgcn_mfma_f32_16x16x32_f16(pa1, fr[bj][1], s4, 0, 0, 0);
#pragma unroll
        for (int r = 0; r < 4; ++r) {
          int irow = bi * 16 + q8 * 4 + r;   // C/D: row=(lane>>4)*4+reg
          int jcol = bj * 16 + m;            //      col=lane&15
          bool valid = (irow < jcol) && (jcol < F_);
          float w = valid ? exp2f(lg[idx][r]) : 0.f;
          num = fmaf(w, s4[r], num);
          den += w;
        }
        ++idx;
      }
    }
  }

  // ---- per-wave reduction only (1 batch per wave) ----
#pragma unroll
  for (int off = 32; off; off >>= 1) {
    num += __shfl_down(num, off);
    den += __shfl_down(den, off);
  }
  if (lane == 0 && bvalid) out[b] = num / den;
}

extern "C" void kernel_launch(void* const* d_in, const int* in_sizes, int n_in,
                              void* d_out, int out_size, void* d_ws, size_t ws_size,
                              hipStream_t stream) {
  const float* x  = (const float*)d_in[0];
  const float* W  = (const float*)d_in[1];
  const float* bb = (const float*)d_in[2];
  const float* h  = (const float*)d_in[3];
  const float* pp = (const float*)d_in[4];
  float* out = (float*)d_out;
  const int nbatch = in_sizes[0] / (F_ * E_);
  const int nblocks = (nbatch + 3) / 4;
  afm_kernel<<<nblocks, NT, 0, stream>>>(x, W, bb, h, pp, out, nbatch);
}

// Round 6
// 86.989 us; speedup vs baseline: 2.0846x; 1.0107x over previous
//
#include <hip/hip_runtime.h>
#include <math.h>

// AFM via Gram MFMA (16x16x32 f16), R6: TWO waves per batch.
//   t_k = X diag(W[:,k]) X^T ; logit = sum_k relu(t_k+b_k) h_k
//   out = (sum_{i<j} exp(logit) s_ij)/(sum exp(logit)), s = X diag(p) X^T
// R6 vs R5 (theory: latency exposure at 2 waves/SIMD):
//  - 2 waves per batch, 5 upper-tri tiles each -> 4096 waves = 4/SIMD
//    (1024 blocks = 4 blocks/CU, ~20 KB LDS, __launch_bounds__(256,4))
//  - staging loop compile-time unrolled (7 iters x 128 threads) so all
//    global loads issue before any dependent use (latency overlap)
// Gram symmetry: one 8-fragment set (32 VGPR) serves both MFMA operands.

#define F_ 50
#define E_ 64
#define A_ 10
#define XSTR 72          // halves; 144 B rows, 16B-aligned
#define NT 256           // 4 waves: 2 batches x 2 waves
#define LOG2E 1.44269504088896f

typedef _Float16 half8 __attribute__((ext_vector_type(8)));
typedef _Float16 half4t __attribute__((ext_vector_type(4)));
typedef float f32x4 __attribute__((ext_vector_type(4)));

// PW=0: tiles (0,0),(0,1),(0,2),(0,3),(1,1)  -> rows {0,1}
// PW=1: tiles (1,2),(1,3),(2,2),(2,3),(3,3)  -> rows {1,2,3}
template <int PW>
__device__ __forceinline__ void compute_half(const _Float16* __restrict__ xb,
                                             const _Float16* __restrict__ sWh,
                                             const float* __restrict__ sb,
                                             const float* __restrict__ sh,
                                             int lane, float& num, float& den) {
  constexpr int TI[5] = { PW ? 1 : 0, PW ? 1 : 0, PW ? 2 : 0, PW ? 2 : 0, PW ? 3 : 1 };
  constexpr int TJ[5] = { PW ? 2 : 0, PW ? 3 : 1, PW ? 2 : 2, PW ? 3 : 3, PW ? 3 : 1 };
  constexpr bool NEED[4] = { PW == 0, true, PW != 0, PW != 0 };

  const int m = lane & 15, q8 = lane >> 4;

  // fragments: A[m][k]: m=lane&15, k=(lane>>4)*8+j — identical for A and B
  half8 fr[4][2];
#pragma unroll
  for (int bi = 0; bi < 4; ++bi)
#pragma unroll
    for (int es = 0; es < 2; ++es)
      fr[bi][es] = *(const half8*)(xb + (bi * 16 + m) * XSTR + es * 32 + q8 * 8);

  float lg[5][4];
#pragma unroll
  for (int tt = 0; tt < 5; ++tt)
#pragma unroll
    for (int r = 0; r < 4; ++r) lg[tt][r] = 0.f;

#pragma unroll 1
  for (int k = 0; k < A_; ++k) {
    half8 wv0 = *(const half8*)(sWh + k * E_ + q8 * 8);       // broadcast
    half8 wv1 = *(const half8*)(sWh + k * E_ + 32 + q8 * 8);
    float bk = sb[k];
    f32x4 ci = { bk, bk, bk, bk };
    half8 sa[4];
#pragma unroll
    for (int bi = 0; bi < 4; ++bi)
      if constexpr (true) { if (NEED[bi]) sa[bi] = fr[bi][0] * wv0; }
    f32x4 t[5];
#pragma unroll
    for (int tt = 0; tt < 5; ++tt)
      t[tt] = __builtin_amdgcn_mfma_f32_16x16x32_f16(sa[TI[tt]], fr[TJ[tt]][0], ci, 0, 0, 0);
#pragma unroll
    for (int bi = 0; bi < 4; ++bi)
      if (NEED[bi]) sa[bi] = fr[bi][1] * wv1;
#pragma unroll
    for (int tt = 0; tt < 5; ++tt)
      t[tt] = __builtin_amdgcn_mfma_f32_16x16x32_f16(sa[TI[tt]], fr[TJ[tt]][1], t[tt], 0, 0, 0);
    float hk = sh[k];   // pre-scaled by log2(e)
#pragma unroll
    for (int tt = 0; tt < 5; ++tt)
#pragma unroll
      for (int r = 0; r < 4; ++r)
        lg[tt][r] = fmaf(fmaxf(t[tt][r], 0.f), hk, lg[tt][r]);
  }

  // proj Gram + masked exp fold
  half8 pv0 = *(const half8*)(sWh + A_ * E_ + q8 * 8);
  half8 pv1 = *(const half8*)(sWh + A_ * E_ + 32 + q8 * 8);
  half8 pa0[4], pa1[4];
#pragma unroll
  for (int bi = 0; bi < 4; ++bi)
    if (NEED[bi]) { pa0[bi] = fr[bi][0] * pv0; pa1[bi] = fr[bi][1] * pv1; }
  f32x4 z4 = { 0.f, 0.f, 0.f, 0.f };
#pragma unroll
  for (int tt = 0; tt < 5; ++tt) {
    f32x4 s4 = __builtin_amdgcn_mfma_f32_16x16x32_f16(pa0[TI[tt]], fr[TJ[tt]][0], z4, 0, 0, 0);
    s4 = __builtin_amdgcn_mfma_f32_16x16x32_f16(pa1[TI[tt]], fr[TJ[tt]][1], s4, 0, 0, 0);
#pragma unroll
    for (int r = 0; r < 4; ++r) {
      int irow = TI[tt] * 16 + q8 * 4 + r;   // C/D: row=(lane>>4)*4+reg
      int jcol = TJ[tt] * 16 + m;            //      col=lane&15
      bool valid = (irow < jcol) && (jcol < F_);
      float w = valid ? exp2f(lg[tt][r]) : 0.f;
      num = fmaf(w, s4[r], num);
      den += w;
    }
  }
}

__global__ __launch_bounds__(NT, 4)
void afm_kernel(const float* __restrict__ x,
                const float* __restrict__ W,
                const float* __restrict__ bias,
                const float* __restrict__ h,
                const float* __restrict__ pp,
                float* __restrict__ out, int nbatch) {
  __shared__ __align__(16) _Float16 sXh[2 * 64 * XSTR];   // 18432 B
  __shared__ __align__(16) _Float16 sWh[(A_ + 1) * E_];   // k<10: W[:,k]; 10: p
  __shared__ float sb[A_], sh[A_];
  __shared__ float rn[4], rd[4];

  const int tid = threadIdx.x;
  const int lane = tid & 63, w4 = tid >> 6;
  const int pair = tid >> 7, t128 = tid & 127;   // 2 waves per batch
  const int b = blockIdx.x * 2 + pair;
  const bool bvalid = b < nbatch;
  _Float16* xb = sXh + pair * (64 * XSTR);

  // ---- stage x: 800 float4 per batch over 128 threads, FULLY UNROLLED
  //      (compile-time trip count -> all 7 global loads issue up-front) ----
  if (bvalid) {
    const float4* xs = (const float4*)(x + (size_t)b * (F_ * E_));
#pragma unroll
    for (int it = 0; it < 7; ++it) {
      int q = t128 + it * 128;
      if (it < 6 || q < F_ * 16) {
        float4 v = xs[q];
        int f = q >> 4, e4 = q & 15;
        half4t hv = { (_Float16)v.x, (_Float16)v.y, (_Float16)v.z, (_Float16)v.w };
        *(half4t*)(xb + f * XSTR + e4 * 4) = hv;
      }
    }
  }
  // zero rows 50..63 (14 rows x 8 half8-chunks = 112 per batch region)
  if (t128 < 112) {
    int f = F_ + (t128 >> 3), c = t128 & 7;
    half8 z = {};
    *(half8*)(xb + f * XSTR + c * 8) = z;
  }
  // stage W (e-major -> k-major fp16) + p as row 10
  if (tid < 11 * 16) {
    int k = tid >> 4, e4 = tid & 15;
    float v0, v1, v2, v3;
    if (k < A_) {
      v0 = W[(e4 * 4 + 0) * A_ + k]; v1 = W[(e4 * 4 + 1) * A_ + k];
      v2 = W[(e4 * 4 + 2) * A_ + k]; v3 = W[(e4 * 4 + 3) * A_ + k];
    } else {
      float4 t4 = *(const float4*)(pp + e4 * 4);
      v0 = t4.x; v1 = t4.y; v2 = t4.z; v3 = t4.w;
    }
    half4t hv = { (_Float16)v0, (_Float16)v1, (_Float16)v2, (_Float16)v3 };
    *(half4t*)(sWh + k * E_ + e4 * 4) = hv;
  }
  if (tid < A_) { sb[tid] = bias[tid]; sh[tid] = h[tid] * LOG2E; }
  __syncthreads();

  float num = 0.f, den = 0.f;
  if (bvalid) {
    if ((w4 & 1) == 0) compute_half<0>(xb, sWh, sb, sh, lane, num, den);
    else               compute_half<1>(xb, sWh, sb, sh, lane, num, den);
  }

  // ---- reduce: wave shuffle -> LDS -> combine the 2 waves of each batch ----
#pragma unroll
  for (int off = 32; off; off >>= 1) {
    num += __shfl_down(num, off);
    den += __shfl_down(den, off);
  }
  if (lane == 0) { rn[w4] = num; rd[w4] = den; }
  __syncthreads();
  if ((tid == 0 || tid == 128) && bvalid)
    out[b] = (rn[pair * 2] + rn[pair * 2 + 1]) / (rd[pair * 2] + rd[pair * 2 + 1]);
}

extern "C" void kernel_launch(void* const* d_in, const int* in_sizes, int n_in,
                              void* d_out, int out_size, void* d_ws, size_t ws_size,
                              hipStream_t stream) {
  const float* x  = (const float*)d_in[0];
  const float* W  = (const float*)d_in[1];
  const float* bb = (const float*)d_in[2];
  const float* h  = (const float*)d_in[3];
  const float* pp = (const float*)d_in[4];
  float* out = (float*)d_out;
  const int nbatch = in_sizes[0] / (F_ * E_);
  const int nblocks = (nbatch + 1) / 2;
  afm_kernel<<<nblocks, NT, 0, stream>>>(x, W, bb, h, pp, out, nbatch);
}

// Round 7
// 86.478 us; speedup vs baseline: 2.0969x; 1.0059x over previous
//
#include <hip/hip_runtime.h>
#include <math.h>

// AFM via Gram MFMA (16x16x32 f16), R7: fragments DIRECT FROM GLOBAL.
//   t_k = X diag(W[:,k]) X^T ; logit = sum_k relu(t_k+b_k) h_k
//   out = (sum_{i<j} exp(logit) s_ij)/(sum exp(logit)), s = X diag(p) X^T
// R7 vs R6 (theory: LDS round-trip for x is pure overhead):
//  - MFMA A/B fragments loaded straight from global x (row=bi*16+(lane&15),
//    col=es*32+(lane>>4)*8, 16B-aligned, LLC-warm from harness restore)
//  - sXh eliminated (18 KB LDS + ~800 ds ops + one barrier removed);
//    rows >= 50 zero-masked at load (only bi==3 block affected)
//  - W/bias/h staging via LDS unchanged (single cheap barrier)
// Gram symmetry: one 8-fragment set (32 VGPR) serves both MFMA operands.

#define F_ 50
#define E_ 64
#define A_ 10
#define NT 256           // 4 waves: 2 batches x 2 waves
#define LOG2E 1.44269504088896f

typedef _Float16 half8 __attribute__((ext_vector_type(8)));
typedef _Float16 half4t __attribute__((ext_vector_type(4)));
typedef float f32x4 __attribute__((ext_vector_type(4)));

// PW=0: tiles (0,0),(0,1),(0,2),(0,3),(1,1)
// PW=1: tiles (1,2),(1,3),(2,2),(2,3),(3,3)
template <int PW>
__device__ __forceinline__ void compute_half(const float* __restrict__ xg,
                                             const _Float16* __restrict__ sWh,
                                             const float* __restrict__ sb,
                                             const float* __restrict__ sh,
                                             int lane, float& num, float& den) {
  constexpr int TI[5] = { PW ? 1 : 0, PW ? 1 : 0, PW ? 2 : 0, PW ? 2 : 0, PW ? 3 : 1 };
  constexpr int TJ[5] = { PW ? 2 : 0, PW ? 3 : 1, PW ? 2 : 2, PW ? 3 : 3, PW ? 3 : 1 };
  constexpr bool NEED[4] = { PW == 0, true, PW != 0, PW != 0 };

  const int m = lane & 15, q8 = lane >> 4;

  // ---- fragments direct from global fp32, cvt to fp16 in regs ----
  // A[m][k]: m=lane&15, k=(lane>>4)*8+j — identical addressing for A and B.
  half8 fr[4][2];
#pragma unroll
  for (int bi = 0; bi < 4; ++bi) {
    const int row = bi * 16 + m;
    const bool rv = (bi < 3) || (m < F_ - 48);   // row < 50
#pragma unroll
    for (int es = 0; es < 2; ++es) {
      float4 v0 = { 0.f, 0.f, 0.f, 0.f }, v1 = v0;
      if (rv) {
        const float* p = xg + row * E_ + es * 32 + q8 * 8;
        v0 = *(const float4*)p;
        v1 = *(const float4*)(p + 4);
      }
      half8 hv = { (_Float16)v0.x, (_Float16)v0.y, (_Float16)v0.z, (_Float16)v0.w,
                   (_Float16)v1.x, (_Float16)v1.y, (_Float16)v1.z, (_Float16)v1.w };
      fr[bi][es] = hv;
    }
  }

  float lg[5][4];
#pragma unroll
  for (int tt = 0; tt < 5; ++tt)
#pragma unroll
    for (int r = 0; r < 4; ++r) lg[tt][r] = 0.f;

#pragma unroll 1
  for (int k = 0; k < A_; ++k) {
    half8 wv0 = *(const half8*)(sWh + k * E_ + q8 * 8);       // broadcast
    half8 wv1 = *(const half8*)(sWh + k * E_ + 32 + q8 * 8);
    float bk = sb[k];
    f32x4 ci = { bk, bk, bk, bk };
    half8 sa[4];
#pragma unroll
    for (int bi = 0; bi < 4; ++bi)
      if (NEED[bi]) sa[bi] = fr[bi][0] * wv0;                 // pk_mul
    f32x4 t[5];
#pragma unroll
    for (int tt = 0; tt < 5; ++tt)
      t[tt] = __builtin_amdgcn_mfma_f32_16x16x32_f16(sa[TI[tt]], fr[TJ[tt]][0], ci, 0, 0, 0);
#pragma unroll
    for (int bi = 0; bi < 4; ++bi)
      if (NEED[bi]) sa[bi] = fr[bi][1] * wv1;
#pragma unroll
    for (int tt = 0; tt < 5; ++tt)
      t[tt] = __builtin_amdgcn_mfma_f32_16x16x32_f16(sa[TI[tt]], fr[TJ[tt]][1], t[tt], 0, 0, 0);
    float hk = sh[k];   // pre-scaled by log2(e)
#pragma unroll
    for (int tt = 0; tt < 5; ++tt)
#pragma unroll
      for (int r = 0; r < 4; ++r)
        lg[tt][r] = fmaf(fmaxf(t[tt][r], 0.f), hk, lg[tt][r]);
  }

  // ---- proj Gram + masked exp fold ----
  half8 pv0 = *(const half8*)(sWh + A_ * E_ + q8 * 8);
  half8 pv1 = *(const half8*)(sWh + A_ * E_ + 32 + q8 * 8);
  half8 pa0[4], pa1[4];
#pragma unroll
  for (int bi = 0; bi < 4; ++bi)
    if (NEED[bi]) { pa0[bi] = fr[bi][0] * pv0; pa1[bi] = fr[bi][1] * pv1; }
  f32x4 z4 = { 0.f, 0.f, 0.f, 0.f };
#pragma unroll
  for (int tt = 0; tt < 5; ++tt) {
    f32x4 s4 = __builtin_amdgcn_mfma_f32_16x16x32_f16(pa0[TI[tt]], fr[TJ[tt]][0], z4, 0, 0, 0);
    s4 = __builtin_amdgcn_mfma_f32_16x16x32_f16(pa1[TI[tt]], fr[TJ[tt]][1], s4, 0, 0, 0);
#pragma unroll
    for (int r = 0; r < 4; ++r) {
      int irow = TI[tt] * 16 + q8 * 4 + r;   // C/D: row=(lane>>4)*4+reg
      int jcol = TJ[tt] * 16 + m;            //      col=lane&15
      bool valid = (irow < jcol) && (jcol < F_);
      float w = valid ? exp2f(lg[tt][r]) : 0.f;
      num = fmaf(w, s4[r], num);
      den += w;
    }
  }
}

__global__ __launch_bounds__(NT, 4)
void afm_kernel(const float* __restrict__ x,
                const float* __restrict__ W,
                const float* __restrict__ bias,
                const float* __restrict__ h,
                const float* __restrict__ pp,
                float* __restrict__ out, int nbatch) {
  __shared__ __align__(16) _Float16 sWh[(A_ + 1) * E_];   // k<10: W[:,k]; 10: p
  __shared__ float sb[A_], sh[A_];
  __shared__ float rn[4], rd[4];

  const int tid = threadIdx.x;
  const int lane = tid & 63, w4 = tid >> 6;
  const int pair = tid >> 7;                 // 2 waves per batch
  const int b = blockIdx.x * 2 + pair;
  const bool bvalid = b < nbatch;

  // ---- stage W (e-major -> k-major fp16) + p as row 10; tiny, one barrier ----
  if (tid < 11 * 16) {
    int k = tid >> 4, e4 = tid & 15;
    float v0, v1, v2, v3;
    if (k < A_) {
      v0 = W[(e4 * 4 + 0) * A_ + k]; v1 = W[(e4 * 4 + 1) * A_ + k];
      v2 = W[(e4 * 4 + 2) * A_ + k]; v3 = W[(e4 * 4 + 3) * A_ + k];
    } else {
      float4 t4 = *(const float4*)(pp + e4 * 4);
      v0 = t4.x; v1 = t4.y; v2 = t4.z; v3 = t4.w;
    }
    half4t hv = { (_Float16)v0, (_Float16)v1, (_Float16)v2, (_Float16)v3 };
    *(half4t*)(sWh + k * E_ + e4 * 4) = hv;
  }
  if (tid < A_) { sb[tid] = bias[tid]; sh[tid] = h[tid] * LOG2E; }
  __syncthreads();

  float num = 0.f, den = 0.f;
  if (bvalid) {
    const float* xg = x + (size_t)b * (F_ * E_);
    if ((w4 & 1) == 0) compute_half<0>(xg, sWh, sb, sh, lane, num, den);
    else               compute_half<1>(xg, sWh, sb, sh, lane, num, den);
  }

  // ---- reduce: wave shuffle -> LDS -> combine the 2 waves of each batch ----
#pragma unroll
  for (int off = 32; off; off >>= 1) {
    num += __shfl_down(num, off);
    den += __shfl_down(den, off);
  }
  if (lane == 0) { rn[w4] = num; rd[w4] = den; }
  __syncthreads();
  if ((tid == 0 || tid == 128) && bvalid)
    out[b] = (rn[pair * 2] + rn[pair * 2 + 1]) / (rd[pair * 2] + rd[pair * 2 + 1]);
}

extern "C" void kernel_launch(void* const* d_in, const int* in_sizes, int n_in,
                              void* d_out, int out_size, void* d_ws, size_t ws_size,
                              hipStream_t stream) {
  const float* x  = (const float*)d_in[0];
  const float* W  = (const float*)d_in[1];
  const float* bb = (const float*)d_in[2];
  const float* h  = (const float*)d_in[3];
  const float* pp = (const float*)d_in[4];
  float* out = (float*)d_out;
  const int nbatch = in_sizes[0] / (F_ * E_);
  const int nblocks = (nbatch + 1) / 2;
  afm_kernel<<<nblocks, NT, 0, stream>>>(x, W, bb, h, pp, out, nbatch);
}